// Round 2
// baseline (1718.038 us; speedup 1.0000x reference)
//
#include <hip/hip_runtime.h>

// AxialAttentionBlock: xs (B=8, C=512, H=128, W=128) fp32, 8 heads, dh=64.
// I/O is fp32 (per reference); internal compute bf16 MFMA.
#define CC   512
#define HWT  16384     // H*W
#define NB   8         // batches
#define DH   64
#define SEQ  128

typedef __bf16 bf16_t;
typedef __bf16 bf16x8 __attribute__((ext_vector_type(8)));
typedef float  f32x4  __attribute__((ext_vector_type(4)));

// ---------------------------------------------------------------------------
// PREP: 8 weight matrices fp32 (C,C) -> bf16, layout unchanged ([n][k]).
// ---------------------------------------------------------------------------
__global__ __launch_bounds__(256) void prep_w_kernel(const float* __restrict__ W0,
                                                     const float* __restrict__ W1,
                                                     const float* __restrict__ W2,
                                                     const float* __restrict__ W3,
                                                     const float* __restrict__ W4,
                                                     const float* __restrict__ W5,
                                                     const float* __restrict__ W6,
                                                     const float* __restrict__ W7,
                                                     bf16_t* __restrict__ Wb) {
  const float* Wsrc[8] = {W0, W1, W2, W3, W4, W5, W6, W7};
  const int w = blockIdx.y;
  const int i = (blockIdx.x * 256 + threadIdx.x) * 4;      // 512*512 elems per W
  float4 v = *(const float4*)(Wsrc[w] + i);
  bf16_t* o = Wb + (size_t)w * (CC * CC) + i;
  o[0] = (bf16_t)v.x; o[1] = (bf16_t)v.y; o[2] = (bf16_t)v.z; o[3] = (bf16_t)v.w;
}

// ---------------------------------------------------------------------------
// T0: xs (b, c, hw) fp32 -> Xt (b, hw, c) bf16   [64x64 LDS tile transpose]
// ---------------------------------------------------------------------------
__global__ __launch_bounds__(256) void t0_kernel(const float* __restrict__ xs,
                                                 bf16_t* __restrict__ Xt) {
  __shared__ bf16_t T[64 * 72];                 // [hw][c], padded stride
  const int hw0 = blockIdx.x * 64, c0 = blockIdx.y * 64;
  const size_t boff = (size_t)blockIdx.z * CC * HWT;
  const int t = threadIdx.x;
  for (int p = 0; p < 4; p++) {
    int job = t + p * 256;                      // 1024 jobs: 64 c-rows x 16 float4
    int c_l = job >> 4, ch = job & 15;
    float4 v = *(const float4*)(xs + boff + (size_t)(c0 + c_l) * HWT + hw0 + ch * 4);
    T[(ch * 4 + 0) * 72 + c_l] = (bf16_t)v.x;
    T[(ch * 4 + 1) * 72 + c_l] = (bf16_t)v.y;
    T[(ch * 4 + 2) * 72 + c_l] = (bf16_t)v.z;
    T[(ch * 4 + 3) * 72 + c_l] = (bf16_t)v.w;
  }
  __syncthreads();
  for (int p = 0; p < 2; p++) {
    int job = t + p * 256;                      // 512 jobs: 64 hw-rows x 8 chunks
    int hw_l = job >> 3, ch = job & 7;
    uint4 v = *(const uint4*)&T[hw_l * 72 + ch * 8];
    *(uint4*)(Xt + boff + (size_t)(hw0 + hw_l) * CC + c0 + ch * 8) = v;
  }
}

// ---------------------------------------------------------------------------
// GEMM: D[b][m][n] = sum_k A[b][m][k] * Wt[n][k]   (all bf16)
//   A: (b, HWT, CC) token-major.  Wt: (CC, CC) [n][k].  D: (b, HWT, CC).
// BM=BN=128, BK=32; 4 waves 2x2; wave tile 64x64 = 4x4 mfma_16x16x32.
// ---------------------------------------------------------------------------
__global__ __launch_bounds__(256) void gemm_kernel(const bf16_t* __restrict__ A,
                                                   const bf16_t* __restrict__ Wt,
                                                   bf16_t* __restrict__ D) {
  __shared__ bf16_t As[128 * 40];               // [row][k], stride 40
  __shared__ bf16_t Ws[128 * 40];
  const int m0 = blockIdx.x * 128, n0 = blockIdx.y * 128;
  const size_t boff = (size_t)blockIdx.z * HWT * CC;
  const bf16_t* Ab = A + boff;
  bf16_t* Db = D + boff;
  const int t = threadIdx.x;
  const int lane = t & 63, wv = t >> 6;
  const int wy = wv >> 1, wx = wv & 1;
  const int r_l = t >> 2, kcol = (t & 3) * 8;
  const int ln15 = lane & 15, q8 = (lane >> 4) * 8;

  f32x4 acc[4][4];
  for (int i = 0; i < 4; i++)
    for (int j = 0; j < 4; j++) acc[i][j] = {0.f, 0.f, 0.f, 0.f};

  for (int kb = 0; kb < 16; kb++) {
    const int kk = kb * 32 + kcol;
    uint4 a0 = *(const uint4*)(Ab + (size_t)(m0 + r_l) * CC + kk);
    uint4 a1 = *(const uint4*)(Ab + (size_t)(m0 + r_l + 64) * CC + kk);
    uint4 w0 = *(const uint4*)(Wt + (size_t)(n0 + r_l) * CC + kk);
    uint4 w1 = *(const uint4*)(Wt + (size_t)(n0 + r_l + 64) * CC + kk);
    __syncthreads();
    *(uint4*)&As[r_l * 40 + kcol] = a0;
    *(uint4*)&As[(r_l + 64) * 40 + kcol] = a1;
    *(uint4*)&Ws[r_l * 40 + kcol] = w0;
    *(uint4*)&Ws[(r_l + 64) * 40 + kcol] = w1;
    __syncthreads();
    bf16x8 af[4], wf[4];
    for (int i = 0; i < 4; i++)
      af[i] = *(const bf16x8*)&As[(wy * 64 + i * 16 + ln15) * 40 + q8];
    for (int j = 0; j < 4; j++)
      wf[j] = *(const bf16x8*)&Ws[(wx * 64 + j * 16 + ln15) * 40 + q8];
    for (int i = 0; i < 4; i++)
      for (int j = 0; j < 4; j++)
        acc[i][j] = __builtin_amdgcn_mfma_f32_16x16x32_bf16(af[i], wf[j], acc[i][j], 0, 0, 0);
  }

  const int qr = (lane >> 4) * 4;
  for (int i = 0; i < 4; i++)
    for (int j = 0; j < 4; j++) {
      const int row = m0 + wy * 64 + i * 16 + qr;
      const int col = n0 + wx * 64 + j * 16 + ln15;
      for (int r = 0; r < 4; r++)
        Db[(size_t)(row + r) * CC + col] = (bf16_t)acc[i][j][r];
    }
}

// ---------------------------------------------------------------------------
// Attention: one block per (o, head, b). S=128, dh=64, full softmax.
//   token(s): b*HWT*CC + o*o_stride + s*seq_stride + head*64
// ---------------------------------------------------------------------------
__global__ __launch_bounds__(256) void attn_kernel(const bf16_t* __restrict__ Q,
                                                   const bf16_t* __restrict__ K,
                                                   const bf16_t* __restrict__ V,
                                                   bf16_t* __restrict__ O,
                                                   int seq_stride, int o_stride) {
  __shared__ bf16_t smem[128 * 72 * 2 + 64 * 136];
  bf16_t* Qs = smem;                 // [128][72]
  bf16_t* Ks = smem + 128 * 72;      // [128][72]
  bf16_t* Vs = smem + 2 * 128 * 72;  // [64][136]  V^T: [d][s']
  bf16_t* Ps = smem;                 // [128][136] aliases Qs+Ks (dead after S)

  const int o = blockIdx.x, head = blockIdx.y;
  const size_t base = (size_t)blockIdx.z * HWT * CC + (size_t)o * o_stride + head * 64;
  const int t = threadIdx.x, lane = t & 63, wv = t >> 6;
  const int ln15 = lane & 15, q = lane >> 4;

  for (int p = 0; p < 4; p++) {
    int job = t + p * 256;
    int s = job >> 3, ch = job & 7;
    uint4 qv = *(const uint4*)(Q + base + (size_t)s * seq_stride + ch * 8);
    uint4 kv = *(const uint4*)(K + base + (size_t)s * seq_stride + ch * 8);
    *(uint4*)&Qs[s * 72 + ch * 8] = qv;
    *(uint4*)&Ks[s * 72 + ch * 8] = kv;
  }
  for (int p = 0; p < 4; p++) {
    int job = t + p * 256;
    int s = job >> 3, ch = job & 7;
    uint4 vv = *(const uint4*)(V + base + (size_t)s * seq_stride + ch * 8);
    const bf16_t* e = (const bf16_t*)&vv;
    for (int jj = 0; jj < 8; jj++) Vs[(ch * 8 + jj) * 136 + s] = e[jj];
  }
  __syncthreads();

  // S = Q K^T
  f32x4 sacc[2][8];
  for (int i = 0; i < 2; i++)
    for (int j = 0; j < 8; j++) sacc[i][j] = {0.f, 0.f, 0.f, 0.f};
  for (int ks = 0; ks < 2; ks++) {
    bf16x8 qf[2], kf[8];
    for (int i = 0; i < 2; i++)
      qf[i] = *(const bf16x8*)&Qs[(wv * 32 + i * 16 + ln15) * 72 + ks * 32 + q * 8];
    for (int j = 0; j < 8; j++)
      kf[j] = *(const bf16x8*)&Ks[(j * 16 + ln15) * 72 + ks * 32 + q * 8];
    for (int i = 0; i < 2; i++)
      for (int j = 0; j < 8; j++)
        sacc[i][j] = __builtin_amdgcn_mfma_f32_16x16x32_bf16(qf[i], kf[j], sacc[i][j], 0, 0, 0);
  }
  __syncthreads();   // everyone done reading Qs/Ks (Ps aliases them)

  // Softmax per row (row lives in a 16-lane quad group)
  const float scale = 0.125f;
  float linv[2][4];
  for (int i = 0; i < 2; i++)
    for (int r = 0; r < 4; r++) {
      float m = -1e30f;
      for (int j = 0; j < 8; j++) m = fmaxf(m, sacc[i][j][r]);
      for (int d = 1; d < 16; d <<= 1) m = fmaxf(m, __shfl_xor(m, d));
      m *= scale;
      float sum = 0.f;
      for (int j = 0; j < 8; j++) {
        float pv = __expf(sacc[i][j][r] * scale - m);
        sacc[i][j][r] = pv;
        sum += pv;
      }
      for (int d = 1; d < 16; d <<= 1) sum += __shfl_xor(sum, d);
      linv[i][r] = 1.f / sum;
    }
  for (int i = 0; i < 2; i++)
    for (int j = 0; j < 8; j++)
      for (int r = 0; r < 4; r++)
        Ps[(wv * 32 + i * 16 + q * 4 + r) * 136 + j * 16 + ln15] = (bf16_t)sacc[i][j][r];
  __syncthreads();

  // O = P V
  f32x4 oacc[2][4];
  for (int i = 0; i < 2; i++)
    for (int j = 0; j < 4; j++) oacc[i][j] = {0.f, 0.f, 0.f, 0.f};
  for (int ks = 0; ks < 4; ks++) {
    bf16x8 pf[2], vf[4];
    for (int i = 0; i < 2; i++)
      pf[i] = *(const bf16x8*)&Ps[(wv * 32 + i * 16 + ln15) * 136 + ks * 32 + q * 8];
    for (int j = 0; j < 4; j++)
      vf[j] = *(const bf16x8*)&Vs[(j * 16 + ln15) * 136 + ks * 32 + q * 8];
    for (int i = 0; i < 2; i++)
      for (int j = 0; j < 4; j++)
        oacc[i][j] = __builtin_amdgcn_mfma_f32_16x16x32_bf16(pf[i], vf[j], oacc[i][j], 0, 0, 0);
  }
  for (int i = 0; i < 2; i++)
    for (int j = 0; j < 4; j++)
      for (int r = 0; r < 4; r++) {
        const int s = wv * 32 + i * 16 + q * 4 + r;
        const int d = j * 16 + ln15;
        O[base + (size_t)s * seq_stride + d] = (bf16_t)(oacc[i][j][r] * linv[i][r]);
      }
}

// ---------------------------------------------------------------------------
// FINAL: out (b,c,hw) fp32 = xs fp32 + OH bf16 (b,hw,c) + OW bf16 (b,hw,c)
// ---------------------------------------------------------------------------
__global__ __launch_bounds__(256) void final_add_kernel(const float* __restrict__ xs,
                                                        const bf16_t* __restrict__ OH,
                                                        const bf16_t* __restrict__ OW,
                                                        float* __restrict__ out) {
  __shared__ float TF[64 * 65];                 // [c][hw], +1 pad
  const int hw0 = blockIdx.x * 64, c0 = blockIdx.y * 64;
  const size_t boff = (size_t)blockIdx.z * CC * HWT;
  const int t = threadIdx.x;
  for (int p = 0; p < 2; p++) {
    int job = t + p * 256;                      // 64 hw-rows x 8 c-chunks
    int hw_l = job >> 3, ch = job & 7;
    size_t off = boff + (size_t)(hw0 + hw_l) * CC + c0 + ch * 8;
    bf16x8 a = *(const bf16x8*)(OH + off);
    bf16x8 b = *(const bf16x8*)(OW + off);
    for (int jj = 0; jj < 8; jj++)
      TF[(ch * 8 + jj) * 65 + hw_l] = (float)a[jj] + (float)b[jj];
  }
  __syncthreads();
  for (int p = 0; p < 4; p++) {
    int job = t + p * 256;                      // 64 c-rows x 16 float4 chunks
    int c_l = job >> 4, ch = job & 15;
    size_t off = boff + (size_t)(c0 + c_l) * HWT + hw0 + ch * 4;
    float4 xv = *(const float4*)(xs + off);
    float4 ov;
    ov.x = xv.x + TF[c_l * 65 + ch * 4 + 0];
    ov.y = xv.y + TF[c_l * 65 + ch * 4 + 1];
    ov.z = xv.z + TF[c_l * 65 + ch * 4 + 2];
    ov.w = xv.w + TF[c_l * 65 + ch * 4 + 3];
    *(float4*)(out + off) = ov;
  }
}

// ---------------------------------------------------------------------------
extern "C" void kernel_launch(void* const* d_in, const int* in_sizes, int n_in,
                              void* d_out, int out_size, void* d_ws, size_t ws_size,
                              hipStream_t stream) {
  const float* xs = (const float*)d_in[0];
  float* out = (float*)d_out;

  // Workspace carve-up: bf16 weights first, then 6 bf16 activation buffers.
  bf16_t* Wb = (bf16_t*)d_ws;                   // 8 * 512*512 bf16 = 4 MiB
  const size_t wbytes = (size_t)8 * CC * CC * sizeof(bf16_t);
  bf16_t* wsb = Wb + (size_t)8 * CC * CC;

  const size_t pb = (size_t)HWT * CC;           // elems per batch per buffer
  size_t avail = (ws_size > wbytes) ? (ws_size - wbytes) : 0;
  int chunkB = (int)(avail / (6 * pb * sizeof(bf16_t)));
  if (chunkB > NB) chunkB = NB;
  if (chunkB < 1) chunkB = 1;
  const size_t R = (size_t)chunkB * pb;
  bf16_t* Xt = wsb;          // reused as OW buffer at the tail
  bf16_t* Qb = wsb + R;
  bf16_t* Kb = wsb + 2 * R;
  bf16_t* Vb = wsb + 3 * R;
  bf16_t* Ab = wsb + 4 * R;
  bf16_t* OH = wsb + 5 * R;

  // Convert weights to bf16: order q_h,k_h,v_h,o_h,q_w,k_w,v_w,o_w
  prep_w_kernel<<<dim3(CC * CC / 1024, 8), 256, 0, stream>>>(
      (const float*)d_in[1], (const float*)d_in[2], (const float*)d_in[3],
      (const float*)d_in[4], (const float*)d_in[5], (const float*)d_in[6],
      (const float*)d_in[7], (const float*)d_in[8], Wb);
  const bf16_t* Wq_h = Wb + 0 * (size_t)CC * CC;
  const bf16_t* Wk_h = Wb + 1 * (size_t)CC * CC;
  const bf16_t* Wv_h = Wb + 2 * (size_t)CC * CC;
  const bf16_t* Wo_h = Wb + 3 * (size_t)CC * CC;
  const bf16_t* Wq_w = Wb + 4 * (size_t)CC * CC;
  const bf16_t* Wk_w = Wb + 5 * (size_t)CC * CC;
  const bf16_t* Wv_w = Wb + 6 * (size_t)CC * CC;
  const bf16_t* Wo_w = Wb + 7 * (size_t)CC * CC;

  for (int b0 = 0; b0 < NB; b0 += chunkB) {
    const int cb = (NB - b0 < chunkB) ? (NB - b0) : chunkB;
    const float* xsc = xs + (size_t)b0 * pb;
    float* outc = out + (size_t)b0 * pb;
    dim3 gT(HWT / 64, CC / 64, cb);
    dim3 gG(HWT / 128, CC / 128, cb);
    dim3 gA(128, 8, cb);
    dim3 blk(256);

    t0_kernel<<<gT, blk, 0, stream>>>(xsc, Xt);
    // height attention (seq along h: stride 128*C; batch pos along w: stride C)
    gemm_kernel<<<gG, blk, 0, stream>>>(Xt, Wq_h, Qb);
    gemm_kernel<<<gG, blk, 0, stream>>>(Xt, Wk_h, Kb);
    gemm_kernel<<<gG, blk, 0, stream>>>(Xt, Wv_h, Vb);
    attn_kernel<<<gA, blk, 0, stream>>>(Qb, Kb, Vb, Ab, 128 * CC, CC);
    gemm_kernel<<<gG, blk, 0, stream>>>(Ab, Wo_h, OH);
    // width attention (seq along w: stride C; batch pos along h: stride 128*C)
    gemm_kernel<<<gG, blk, 0, stream>>>(Xt, Wq_w, Qb);
    gemm_kernel<<<gG, blk, 0, stream>>>(Xt, Wk_w, Kb);
    gemm_kernel<<<gG, blk, 0, stream>>>(Xt, Wv_w, Vb);
    attn_kernel<<<gA, blk, 0, stream>>>(Qb, Kb, Vb, Ab, CC, 128 * CC);
    gemm_kernel<<<gG, blk, 0, stream>>>(Ab, Wo_w, Xt);   // OW -> Xt (dead)
    final_add_kernel<<<gT, blk, 0, stream>>>(xsc, OH, Xt, outc);
  }
}